// Round 7
// baseline (215.110 us; speedup 1.0000x reference)
//
#include <hip/hip_runtime.h>
#include <hip/hip_bf16.h>
#include <stdint.h>

#define N_   64
#define L_   1024
#define D_   512
#define S_   127
#define OUT_ 300
#define NT_  20            // 20 col-tiles of 16 -> 320 padded cols
#define OUTP (NT_*16)      // 320
#define EPS_ 1e-5f
#define M_TOTAL (N_*S_)    // 8128

// prep kernel block ranges
#define WBLK 640           // OUTP*D_/256 : w_lin f32 -> bf16 K-major
#define UBLK 32            // N_*D_/4/256 : use = t1[:,0,:]

// fused main kernel
#define BM   16
#define GBLK (M_TOTAL/BM)  // 508 blocks
#define BK   64            // K-tile
#define NKT  (D_/BK)       // 8
#define ASTR 72            // A row stride (bf16): 144 B, 16B-aligned
#define HSTR 320           // epilogue h stride (floats)
#define LDS_A_BYTES (BM*ASTR*2)        // 2304
#define LDS_H_BYTES (BM*HSTR*4)       // 20480
#define LDS_TOTAL   (LDS_A_BYTES + LDS_H_BYTES)   // 22784 -> not limiting

typedef __attribute__((ext_vector_type(4))) float  float4v;
typedef __attribute__((ext_vector_type(8))) __bf16 bf16x8;
typedef __attribute__((ext_vector_type(4))) __bf16 bf16x4;

// ---------------------------------------------------------------------------
// prep_small: (a) w_lin f32 -> bf16, K-MAJOR wbf[kt][o][kk] (kt=d>>6,kk=d&63)
// so B fragments are small contiguous chunks per lane; (b) use = t1[:,0,:].
// ---------------------------------------------------------------------------
__global__ __launch_bounds__(256) void prep_small(
    const float* __restrict__ t1, const float* __restrict__ w_lin,
    __bf16* __restrict__ wbf, float* __restrict__ use_out)
{
    const int blk = blockIdx.x;
    const int tid = threadIdx.x;
    if (blk < WBLK) {                       // --- w_lin -> bf16 K-major
        int idx = blk * 256 + tid;          // 320*512 threads
        int o = idx >> 9, d = idx & (D_ - 1);
        float v = (o < OUT_) ? w_lin[o * D_ + d] : 0.0f;
        wbf[((size_t)(d >> 6) * OUTP + o) * BK + (d & 63)] = (__bf16)v;
    } else {                                // --- use = t1[:,0,:]
        int idx = (blk - WBLK) * 256 + tid; // 8192 threads, float4 each
        int n = idx >> 7, dg = idx & 127;
        float4v v = *(const float4v*)(t1 + (size_t)n * L_ * D_ + dg * 4);
        *(float4v*)(use_out + n * D_ + dg * 4) = v;
    }
}

// ---------------------------------------------------------------------------
// enc_v6: r5's interleaved structure with the B LDS round-trip DELETED.
// B fragments are loaded per-lane straight from L2-resident K-major wbf into
// bload[10] registers one tile ahead (rotated right after each MFMA consumes
// the old value). Barriers only protect the 2.3 KB A tile. LDS 22.8 KB,
// ~117 VGPR -> 16 waves/CU.
// ---------------------------------------------------------------------------
__global__ __launch_bounds__(256, 4) void enc_v6(
    const float* __restrict__ t1, const int* __restrict__ wseq,
    const __bf16* __restrict__ wbf, const float* __restrict__ b_lin,
    const float* __restrict__ gamma, const float* __restrict__ beta,
    float* __restrict__ out)
{
    __shared__ __align__(16) char smem[LDS_TOTAL];
    __bf16* Alds = (__bf16*)smem;                    // [16][72]
    float*  hlds = (float*)(smem + LDS_A_BYTES);     // [16][320]

    const int tid  = threadIdx.x;
    const int m0   = blockIdx.x * BM;
    const int lane = tid & 63;
    const int wave = tid >> 6;         // 0..3 -> col tiles [wave*5, wave*5+5)
    const int quad = lane >> 4;
    const int ln16 = lane & 15;

    // ---- A staging role: one (row, 16B k-group) per thread
    const int ar  = tid >> 4;          // 0..15
    const int akg = tid & 15;          // 0..15 -> covers 64 floats = BK
    const int sp  = m0 + ar;
    const int nn  = sp / S_;
    const int2 wv = *(const int2*)(wseq + sp * 2);
    const int st  = min(wv.x, L_ - 3);
    const int en  = min(wv.y, L_ - 2);
    const int cnt = en - st;
    const float inv = 1.0f / (float)cnt;
    const float* abase = t1 + ((size_t)nn * L_ + 1 + st) * D_ + akg * 4;

    // ---- per-lane B base: this wave's col rows, K-major fragments
    // fragment (i,ks) of tile kt at byte offset kt*40960 + i*2048 + ks*64
    const char* bptr = (const char*)(wbf + (size_t)(wave * 80 + ln16) * BK + quad * 8);

    // ---- prologue: prefetch tile 0 (A to regs, B to regs)
    float4v aload[8];
    #pragma unroll
    for (int j = 0; j < 8; ++j) {
        int jj = (j < cnt) ? j : (cnt - 1);        // clamp keeps addr in-bounds
        aload[j] = *(const float4v*)(abase + jj * D_);
    }
    bf16x8 bload[10];
    #pragma unroll
    for (int ks = 0; ks < 2; ++ks)
        #pragma unroll
        for (int i = 0; i < 5; ++i)
            bload[ks * 5 + i] = *(const bf16x8*)(bptr + i * 2048 + ks * 64);

    float4v acc[5];
    #pragma unroll
    for (int i = 0; i < 5; ++i) acc[i] = float4v{0.f, 0.f, 0.f, 0.f};

    #pragma unroll
    for (int kt = 0; kt < NKT; ++kt) {
        // ---- commit A tile kt from regs to LDS
        float4v s4 = {0.f, 0.f, 0.f, 0.f};
        #pragma unroll
        for (int j = 0; j < 8; ++j)
            if (j < cnt) s4 += aload[j];
        s4 *= inv;
        bf16x4 a4;
        a4[0] = (__bf16)s4[0]; a4[1] = (__bf16)s4[1];
        a4[2] = (__bf16)s4[2]; a4[3] = (__bf16)s4[3];
        *(bf16x4*)(Alds + ar * ASTR + akg * 4) = a4;
        __syncthreads();   // barrier #1 — A tile kt visible

        // ---- prefetch A for tile kt+1 (regs survive barriers)
        if (kt < NKT - 1) {
            #pragma unroll
            for (int j = 0; j < 8; ++j) {
                int jj = (j < cnt) ? j : (cnt - 1);
                aload[j] = *(const float4v*)(abase + (kt + 1) * BK + jj * D_);
            }
        }

        // ---- MFMA tile kt; rotate each B fragment to tile kt+1 after use
        const char* bnext = bptr + (size_t)(kt + 1) * (OUTP * BK * 2);
        #pragma unroll
        for (int ks = 0; ks < 2; ++ks) {
            bf16x8 af = *(const bf16x8*)(Alds + ln16 * ASTR + ks * 32 + quad * 8);
            #pragma unroll
            for (int i = 0; i < 5; ++i) {
                acc[i] = __builtin_amdgcn_mfma_f32_16x16x32_bf16(af, bload[ks * 5 + i], acc[i], 0, 0, 0);
                if (kt < NKT - 1)
                    bload[ks * 5 + i] = *(const bf16x8*)(bnext + i * 2048 + ks * 64);
            }
        }
        __syncthreads();   // barrier #2 — A reads done before next overwrite
    }

    // ---- epilogue: h = acc + bias (C layout: row = quad*4+reg, col = ln16)
    #pragma unroll
    for (int i = 0; i < 5; ++i) {
        const int col = (wave * 5 + i) * 16 + ln16;
        const float bl = (col < OUT_) ? b_lin[col] : 0.0f;
        #pragma unroll
        for (int r = 0; r < 4; ++r)
            hlds[(quad * 4 + r) * HSTR + col] = acc[i][r] + bl;
    }
    __syncthreads();

    // ---- LayerNorm over 300 cols; 16 threads/row, shfl-reduce in 16-lane groups
    const int r  = tid >> 4;           // 0..15
    const int c0 = tid & 15;
    float sum = 0.f, sq = 0.f;
    #pragma unroll
    for (int i = 0; i < 19; ++i) {
        int c = c0 + 16 * i;
        if (c < OUT_) { float v = hlds[r * HSTR + c]; sum += v; sq += v * v; }
    }
    #pragma unroll
    for (int off = 8; off > 0; off >>= 1) {
        sum += __shfl_xor(sum, off);
        sq  += __shfl_xor(sq,  off);
    }
    const float mu  = sum * (1.0f / OUT_);
    const float var = sq * (1.0f / OUT_) - mu * mu;
    const float rs  = rsqrtf(var + EPS_);
    float* orow = out + (size_t)(m0 + r) * OUT_;
    #pragma unroll
    for (int i = 0; i < 19; ++i) {
        int c = c0 + 16 * i;
        if (c < OUT_) {
            float v = hlds[r * HSTR + c];
            orow[c] = (v - mu) * rs * gamma[c] + beta[c];
        }
    }
}

extern "C" void kernel_launch(void* const* d_in, const int* in_sizes, int n_in,
                              void* d_out, int out_size, void* d_ws, size_t ws_size,
                              hipStream_t stream) {
    const float* t1    = (const float*)d_in[0];
    const int*   wseq  = (const int*)d_in[1];   // word_seq (int32); d_in[2] mask unused
    const float* w_lin = (const float*)d_in[3];
    const float* b_lin = (const float*)d_in[4];
    const float* gamma = (const float*)d_in[5];
    const float* beta  = (const float*)d_in[6];
    float* out  = (float*)d_out;
    __bf16* wbf = (__bf16*)d_ws;                // 8*320*64*2 = 327680 B scratch

    prep_small<<<WBLK + UBLK, 256, 0, stream>>>(t1, w_lin, wbf,
                                                out + (size_t)M_TOTAL * OUT_);
    enc_v6<<<GBLK, 256, 0, stream>>>(t1, wseq, wbf, b_lin, gamma, beta, out);
}

// Round 8
// 210.814 us; speedup vs baseline: 1.0204x; 1.0204x over previous
//
#include <hip/hip_runtime.h>
#include <hip/hip_bf16.h>
#include <stdint.h>

#define N_   64
#define L_   1024
#define D_   512
#define S_   127
#define OUT_ 300
#define NT_  20            // 20 col-tiles of 16 -> 320 padded cols
#define OUTP (NT_*16)      // 320
#define EPS_ 1e-5f
#define M_TOTAL (N_*S_)    // 8128

// prep kernel block ranges
#define WBLK 640           // OUTP*D_/256 : w_lin f32 -> bf16 K-major
#define UBLK 32            // N_*D_/4/256 : use = t1[:,0,:]

// fused main kernel
#define BM   16
#define GBLK (M_TOTAL/BM)  // 508 blocks
#define BK   64            // K-tile
#define NKT  (D_/BK)       // 8
#define ASTR 72            // A row stride (bf16): 144 B, 16B-aligned
#define HSTR 320           // epilogue h stride (floats)
#define LDS_A_BYTES (BM*ASTR*2)   // 2304
#define LDS_B_BYTES (OUTP*BK*2)   // 40960 (linear + XOR swizzle)
#define LDS_TOTAL   (LDS_A_BYTES + LDS_B_BYTES)   // 43264

typedef __attribute__((ext_vector_type(4))) float  float4v;
typedef __attribute__((ext_vector_type(8))) __bf16 bf16x8;
typedef __attribute__((ext_vector_type(4))) __bf16 bf16x4;

// ---------------------------------------------------------------------------
// prep_small: (a) w_lin f32 -> bf16, K-MAJOR wbf[kt][o][kk] (kt=d>>6,kk=d&63)
// so per-tile B staging is ONE contiguous 40 KB stream; (b) use = t1[:,0,:].
// ---------------------------------------------------------------------------
__global__ __launch_bounds__(256) void prep_small(
    const float* __restrict__ t1, const float* __restrict__ w_lin,
    __bf16* __restrict__ wbf, float* __restrict__ use_out)
{
    const int blk = blockIdx.x;
    const int tid = threadIdx.x;
    if (blk < WBLK) {                       // --- w_lin -> bf16 K-major
        int idx = blk * 256 + tid;          // 320*512 threads
        int o = idx >> 9, d = idx & (D_ - 1);
        float v = (o < OUT_) ? w_lin[o * D_ + d] : 0.0f;
        wbf[((size_t)(d >> 6) * OUTP + o) * BK + (d & 63)] = (__bf16)v;
    } else {                                // --- use = t1[:,0,:]
        int idx = (blk - WBLK) * 256 + tid; // 8192 threads, float4 each
        int n = idx >> 7, dg = idx & 127;
        float4v v = *(const float4v*)(t1 + (size_t)n * L_ * D_ + dg * 4);
        *(float4v*)(use_out + n * D_ + dg * 4) = v;
    }
}

// ---------------------------------------------------------------------------
// enc_v7: EXACTLY r5's structure (best measured: interleaved pacing, B via
// swizzled LDS, 2 barriers/tile) with ONE change: 2-DEEP A prefetch.
// Tile kt's A loads are issued two tiles early (ping-pong reg buffers aA/aB)
// so the A-commit vmcnt wait has a ~2-tile covering window instead of ~200cy.
// B refill issued first after the barrier (needs only a 1-tile L2 window).
// ---------------------------------------------------------------------------
__global__ __launch_bounds__(256, 3) void enc_v7(
    const float* __restrict__ t1, const int* __restrict__ wseq,
    const __bf16* __restrict__ wbf, const float* __restrict__ b_lin,
    const float* __restrict__ gamma, const float* __restrict__ beta,
    float* __restrict__ out)
{
    __shared__ __align__(16) char smem[LDS_TOTAL];
    __bf16* Alds  = (__bf16*)smem;              // [16][72]
    char*   Bbase = smem + LDS_A_BYTES;         // [320][128B] swizzled
    float*  hlds  = (float*)Bbase;              // [16][320] aliases B after k-loop

    const int tid  = threadIdx.x;
    const int m0   = blockIdx.x * BM;
    const int lane = tid & 63;
    const int wave = tid >> 6;         // 0..3 -> col tiles [wave*5, wave*5+5)
    const int quad = lane >> 4;
    const int ln16 = lane & 15;

    // ---- A staging role: one (row, 16B k-group) per thread
    const int ar  = tid >> 4;          // 0..15
    const int akg = tid & 15;          // 0..15 -> covers 64 floats = BK
    const int sp  = m0 + ar;
    const int nn  = sp / S_;
    const int2 wv = *(const int2*)(wseq + sp * 2);
    const int st  = min(wv.x, L_ - 3);
    const int en  = min(wv.y, L_ - 2);
    const int cnt = en - st;
    const float inv = 1.0f / (float)cnt;
    const float* abase = t1 + ((size_t)nn * L_ + 1 + st) * D_ + akg * 4;

    // ---- prologue: A tiles 0,1 and B tile 0 into registers
    float4v aA[8], aB[8];              // ping-pong A prefetch buffers
    #pragma unroll
    for (int j = 0; j < 8; ++j) {
        int jj = (j < cnt) ? j : (cnt - 1);        // clamp keeps addr in-bounds
        aA[j] = *(const float4v*)(abase + jj * D_);
    }
    bf16x8 bload[10];
    #pragma unroll
    for (int it = 0; it < 10; ++it)
        bload[it] = *(const bf16x8*)(wbf + (size_t)(tid + it * 256) * 8);
    #pragma unroll
    for (int j = 0; j < 8; ++j) {
        int jj = (j < cnt) ? j : (cnt - 1);
        aB[j] = *(const float4v*)(abase + BK + jj * D_);
    }

    float4v acc[5];
    #pragma unroll
    for (int i = 0; i < 5; ++i) acc[i] = float4v{0.f, 0.f, 0.f, 0.f};

    #pragma unroll
    for (int kt = 0; kt < NKT; ++kt) {
        float4v* aold = (kt & 1) ? aB : aA;    // holds tile kt (static under unroll)

        // ---- commit tile kt: A mean -> LDS, B regs -> swizzled LDS
        float4v s4 = {0.f, 0.f, 0.f, 0.f};
        #pragma unroll
        for (int j = 0; j < 8; ++j)
            if (j < cnt) s4 += aold[j];
        s4 *= inv;
        bf16x4 a4;
        a4[0] = (__bf16)s4[0]; a4[1] = (__bf16)s4[1];
        a4[2] = (__bf16)s4[2]; a4[3] = (__bf16)s4[3];
        *(bf16x4*)(Alds + ar * ASTR + akg * 4) = a4;

        #pragma unroll
        for (int it = 0; it < 10; ++it) {
            int g   = tid + it * 256;                       // 16B group, row = g>>3
            int off = (g * 16) ^ (((g >> 3) & 7) << 4);     // XOR swizzle
            *(bf16x8*)(Bbase + off) = bload[it];
        }
        __syncthreads();   // barrier #1 — tile kt visible

        // ---- refill B for tile kt+1 (1-tile window, L2) FIRST...
        if (kt < NKT - 1) {
            const __bf16* bsrc = wbf + (size_t)(kt + 1) * OUTP * BK;
            #pragma unroll
            for (int it = 0; it < 10; ++it)
                bload[it] = *(const bf16x8*)(bsrc + (size_t)(tid + it * 256) * 8);
        }
        // ---- ...then refill the just-freed A buffer with tile kt+2 (2-tile window)
        if (kt < NKT - 2) {
            #pragma unroll
            for (int j = 0; j < 8; ++j) {
                int jj = (j < cnt) ? j : (cnt - 1);
                aold[j] = *(const float4v*)(abase + (kt + 2) * BK + jj * D_);
            }
        }

        // ---- MFMA tile kt: 2 k-steps x 5 col-tiles (identical to r5)
        #pragma unroll
        for (int ks = 0; ks < 2; ++ks) {
            bf16x8 af = *(const bf16x8*)(Alds + ln16 * ASTR + ks * 32 + quad * 8);
            #pragma unroll
            for (int i = 0; i < 5; ++i) {
                const int orow = (wave * 5 + i) * 16 + ln16;
                const int slot = ((ks * 4 + quad) ^ (orow & 7)) << 4;
                bf16x8 bfr = *(const bf16x8*)(Bbase + orow * 128 + slot);
                acc[i] = __builtin_amdgcn_mfma_f32_16x16x32_bf16(af, bfr, acc[i], 0, 0, 0);
            }
        }
        __syncthreads();   // barrier #2 — reads done before next tile overwrite
    }

    // ---- epilogue: h = acc + bias (C layout: row = quad*4+reg, col = ln16)
    #pragma unroll
    for (int i = 0; i < 5; ++i) {
        const int col = (wave * 5 + i) * 16 + ln16;
        const float bl = (col < OUT_) ? b_lin[col] : 0.0f;
        #pragma unroll
        for (int r = 0; r < 4; ++r)
            hlds[(quad * 4 + r) * HSTR + col] = acc[i][r] + bl;
    }
    __syncthreads();

    // ---- LayerNorm over 300 cols; 16 threads/row, shfl-reduce in 16-lane groups
    const int r  = tid >> 4;           // 0..15
    const int c0 = tid & 15;
    float sum = 0.f, sq = 0.f;
    #pragma unroll
    for (int i = 0; i < 19; ++i) {
        int c = c0 + 16 * i;
        if (c < OUT_) { float v = hlds[r * HSTR + c]; sum += v; sq += v * v; }
    }
    #pragma unroll
    for (int off = 8; off > 0; off >>= 1) {
        sum += __shfl_xor(sum, off);
        sq  += __shfl_xor(sq,  off);
    }
    const float mu  = sum * (1.0f / OUT_);
    const float var = sq * (1.0f / OUT_) - mu * mu;
    const float rs  = rsqrtf(var + EPS_);
    float* orow = out + (size_t)(m0 + r) * OUT_;
    #pragma unroll
    for (int i = 0; i < 19; ++i) {
        int c = c0 + 16 * i;
        if (c < OUT_) {
            float v = hlds[r * HSTR + c];
            orow[c] = (v - mu) * rs * gamma[c] + beta[c];
        }
    }
}

extern "C" void kernel_launch(void* const* d_in, const int* in_sizes, int n_in,
                              void* d_out, int out_size, void* d_ws, size_t ws_size,
                              hipStream_t stream) {
    const float* t1    = (const float*)d_in[0];
    const int*   wseq  = (const int*)d_in[1];   // word_seq (int32); d_in[2] mask unused
    const float* w_lin = (const float*)d_in[3];
    const float* b_lin = (const float*)d_in[4];
    const float* gamma = (const float*)d_in[5];
    const float* beta  = (const float*)d_in[6];
    float* out  = (float*)d_out;
    __bf16* wbf = (__bf16*)d_ws;                // 8*320*64*2 = 327680 B scratch

    prep_small<<<WBLK + UBLK, 256, 0, stream>>>(t1, w_lin, wbf,
                                                out + (size_t)M_TOTAL * OUT_);
    enc_v7<<<GBLK, 256, 0, stream>>>(t1, wseq, wbf, b_lin, gamma, beta, out);
}

// Round 9
// 209.760 us; speedup vs baseline: 1.0255x; 1.0050x over previous
//
#include <hip/hip_runtime.h>
#include <hip/hip_bf16.h>
#include <stdint.h>

#define N_   64
#define L_   1024
#define D_   512
#define S_   127
#define OUT_ 300
#define NT_  20            // 20 col-tiles of 16 -> 320 padded cols
#define OUTP (NT_*16)      // 320
#define EPS_ 1e-5f
#define M_TOTAL (N_*S_)    // 8128

// prep kernel block ranges
#define WBLK 640           // OUTP*D_/256 : w_lin f32 -> bf16 K-major
#define UBLK 32            // N_*D_/4/256 : use = t1[:,0,:]

// fused main kernel
#define BM   32
#define GBLK (M_TOTAL/BM)  // 254 blocks x 512 thr (8 waves)
#define BK   64            // K-tile
#define NKT  (D_/BK)       // 8
#define ASTR 72            // A row stride (bf16): 144 B, 16B-aligned
#define HSTR 320           // epilogue h stride (floats)
#define LDS_A_BYTES (BM*ASTR*2)   // 4608
#define LDS_B_BYTES (OUTP*BK*2)   // 40960 (linear + XOR swizzle)
#define LDS_TOTAL   (LDS_A_BYTES + LDS_B_BYTES)   // 45568

typedef __attribute__((ext_vector_type(4))) float  float4v;
typedef __attribute__((ext_vector_type(8))) __bf16 bf16x8;
typedef __attribute__((ext_vector_type(4))) __bf16 bf16x4;

// ---------------------------------------------------------------------------
// prep_small: (a) w_lin f32 -> bf16, K-MAJOR wbf[kt][o][kk] (kt=d>>6,kk=d&63)
// so per-tile B staging is ONE contiguous 40 KB stream; (b) use = t1[:,0,:].
// ---------------------------------------------------------------------------
__global__ __launch_bounds__(256) void prep_small(
    const float* __restrict__ t1, const float* __restrict__ w_lin,
    __bf16* __restrict__ wbf, float* __restrict__ use_out)
{
    const int blk = blockIdx.x;
    const int tid = threadIdx.x;
    if (blk < WBLK) {                       // --- w_lin -> bf16 K-major
        int idx = blk * 256 + tid;          // 320*512 threads
        int o = idx >> 9, d = idx & (D_ - 1);
        float v = (o < OUT_) ? w_lin[o * D_ + d] : 0.0f;
        wbf[((size_t)(d >> 6) * OUTP + o) * BK + (d & 63)] = (__bf16)v;
    } else {                                // --- use = t1[:,0,:]
        int idx = (blk - WBLK) * 256 + tid; // 8192 threads, float4 each
        int n = idx >> 7, dg = idx & 127;
        float4v v = *(const float4v*)(t1 + (size_t)n * L_ * D_ + dg * 4);
        *(float4v*)(use_out + n * D_ + dg * 4) = v;
    }
}

// ---------------------------------------------------------------------------
// enc_v8: r5's proven pacing structure at BM=32/512thr, halving the wbf
// re-read (254 x 320 KB = 81 MB vs 163 MB) and the per-row barrier count.
// Per K-tile: {commit A-mean + B regs->LDS, barrier, prefetch kt+1 to regs,
// MFMA from LDS, barrier}. B-LDS linear [320][128B], byte ^= (row&7)<<4.
// waves/CU unchanged vs r5 (8). All index math verified in r5/r6.
// ---------------------------------------------------------------------------
__global__ __launch_bounds__(512, 2) void enc_v8(
    const float* __restrict__ t1, const int* __restrict__ wseq,
    const __bf16* __restrict__ wbf, const float* __restrict__ b_lin,
    const float* __restrict__ gamma, const float* __restrict__ beta,
    float* __restrict__ out)
{
    __shared__ __align__(16) char smem[LDS_TOTAL];
    __bf16* Alds  = (__bf16*)smem;              // [32][72]
    char*   Bbase = smem + LDS_A_BYTES;         // [320][128B] swizzled
    float*  hlds  = (float*)Bbase;              // [32][320] aliases B after k-loop

    const int tid  = threadIdx.x;
    const int m0   = blockIdx.x * BM;
    const int lane = tid & 63;
    const int wave = tid >> 6;         // 0..7
    const int quad = lane >> 4;
    const int ln16 = lane & 15;
    const int rt   = wave >> 2;        // row tile 0..1 (16 rows each)
    const int cg   = wave & 3;         // col group -> tiles [cg*5, cg*5+5)

    // ---- A staging role: one (row, 16B k-group) per thread; 32x16 = 512
    const int ar  = tid >> 4;          // 0..31
    const int akg = tid & 15;          // 0..15 -> covers 64 floats = BK
    const int sp  = m0 + ar;
    const int nn  = sp / S_;
    const int2 wv = *(const int2*)(wseq + sp * 2);
    const int st  = min(wv.x, L_ - 3);
    const int en  = min(wv.y, L_ - 2);
    const int cnt = en - st;
    const float inv = 1.0f / (float)cnt;
    const float* abase = t1 + ((size_t)nn * L_ + 1 + st) * D_ + akg * 4;

    // ---- prologue: prefetch tile 0 into registers
    float4v aload[8];
    #pragma unroll
    for (int j = 0; j < 8; ++j) {
        int jj = (j < cnt) ? j : (cnt - 1);        // clamp keeps addr in-bounds
        aload[j] = *(const float4v*)(abase + jj * D_);
    }
    bf16x8 bload[5];
    #pragma unroll
    for (int it = 0; it < 5; ++it)
        bload[it] = *(const bf16x8*)(wbf + (size_t)(tid + it * 512) * 8);

    float4v acc[5];
    #pragma unroll
    for (int i = 0; i < 5; ++i) acc[i] = float4v{0.f, 0.f, 0.f, 0.f};

    #pragma unroll
    for (int kt = 0; kt < NKT; ++kt) {
        // ---- commit tile kt: A mean -> LDS, B regs -> swizzled LDS
        float4v s4 = {0.f, 0.f, 0.f, 0.f};
        #pragma unroll
        for (int j = 0; j < 8; ++j)
            if (j < cnt) s4 += aload[j];
        s4 *= inv;
        bf16x4 a4;
        a4[0] = (__bf16)s4[0]; a4[1] = (__bf16)s4[1];
        a4[2] = (__bf16)s4[2]; a4[3] = (__bf16)s4[3];
        *(bf16x4*)(Alds + ar * ASTR + akg * 4) = a4;

        #pragma unroll
        for (int it = 0; it < 5; ++it) {
            int g   = tid + it * 512;                       // 16B group, row = g>>3
            int off = (g * 16) ^ (((g >> 3) & 7) << 4);     // XOR swizzle
            *(bf16x8*)(Bbase + off) = bload[it];
        }
        __syncthreads();   // barrier #1 — tile kt visible

        // ---- prefetch tile kt+1 (regs survive barriers): B first, then A
        if (kt < NKT - 1) {
            const __bf16* bsrc = wbf + (size_t)(kt + 1) * OUTP * BK;
            #pragma unroll
            for (int it = 0; it < 5; ++it)
                bload[it] = *(const bf16x8*)(bsrc + (size_t)(tid + it * 512) * 8);
            #pragma unroll
            for (int j = 0; j < 8; ++j) {
                int jj = (j < cnt) ? j : (cnt - 1);
                aload[j] = *(const float4v*)(abase + (kt + 1) * BK + jj * D_);
            }
        }

        // ---- MFMA tile kt: 2 k-steps x 5 col-tiles (r6-verified indexing)
        #pragma unroll
        for (int ks = 0; ks < 2; ++ks) {
            bf16x8 af = *(const bf16x8*)(Alds + (rt * 16 + ln16) * ASTR
                                              + ks * 32 + quad * 8);
            #pragma unroll
            for (int i = 0; i < 5; ++i) {
                const int orow = (cg * 5 + i) * 16 + ln16;
                const int slot = ((ks * 4 + quad) ^ (orow & 7)) << 4;
                bf16x8 bfr = *(const bf16x8*)(Bbase + orow * 128 + slot);
                acc[i] = __builtin_amdgcn_mfma_f32_16x16x32_bf16(af, bfr, acc[i], 0, 0, 0);
            }
        }
        __syncthreads();   // barrier #2 — reads done before next tile overwrite
    }

    // ---- epilogue: h = acc + bias (C layout: row = quad*4+reg, col = ln16)
    #pragma unroll
    for (int i = 0; i < 5; ++i) {
        const int col = (cg * 5 + i) * 16 + ln16;
        const float bl = (col < OUT_) ? b_lin[col] : 0.0f;
        #pragma unroll
        for (int r = 0; r < 4; ++r)
            hlds[(rt * 16 + quad * 4 + r) * HSTR + col] = acc[i][r] + bl;
    }
    __syncthreads();

    // ---- LayerNorm over 300 cols; 16 threads/row, shfl-reduce in 16-lane groups
    const int r  = tid >> 4;           // 0..31
    const int c0 = tid & 15;
    float sum = 0.f, sq = 0.f;
    #pragma unroll
    for (int i = 0; i < 19; ++i) {
        int c = c0 + 16 * i;
        if (c < OUT_) { float v = hlds[r * HSTR + c]; sum += v; sq += v * v; }
    }
    #pragma unroll
    for (int off = 8; off > 0; off >>= 1) {
        sum += __shfl_xor(sum, off);
        sq  += __shfl_xor(sq,  off);
    }
    const float mu  = sum * (1.0f / OUT_);
    const float var = sq * (1.0f / OUT_) - mu * mu;
    const float rs  = rsqrtf(var + EPS_);
    float* orow = out + (size_t)(m0 + r) * OUT_;
    #pragma unroll
    for (int i = 0; i < 19; ++i) {
        int c = c0 + 16 * i;
        if (c < OUT_) {
            float v = hlds[r * HSTR + c];
            orow[c] = (v - mu) * rs * gamma[c] + beta[c];
        }
    }
}

extern "C" void kernel_launch(void* const* d_in, const int* in_sizes, int n_in,
                              void* d_out, int out_size, void* d_ws, size_t ws_size,
                              hipStream_t stream) {
    const float* t1    = (const float*)d_in[0];
    const int*   wseq  = (const int*)d_in[1];   // word_seq (int32); d_in[2] mask unused
    const float* w_lin = (const float*)d_in[3];
    const float* b_lin = (const float*)d_in[4];
    const float* gamma = (const float*)d_in[5];
    const float* beta  = (const float*)d_in[6];
    float* out  = (float*)d_out;
    __bf16* wbf = (__bf16*)d_ws;                // 8*320*64*2 = 327680 B scratch

    prep_small<<<WBLK + UBLK, 256, 0, stream>>>(t1, w_lin, wbf,
                                                out + (size_t)M_TOTAL * OUT_);
    enc_v8<<<GBLK, 512, 0, stream>>>(t1, wseq, wbf, b_lin, gamma, beta, out);
}

// Round 10
// 209.632 us; speedup vs baseline: 1.0261x; 1.0006x over previous
//
#include <hip/hip_runtime.h>
#include <hip/hip_bf16.h>
#include <stdint.h>

#define N_   64
#define L_   1024
#define D_   512
#define S_   127
#define OUT_ 300
#define NT_  20            // 20 col-tiles of 16 -> 320 padded cols
#define OUTP (NT_*16)      // 320
#define EPS_ 1e-5f
#define M_TOTAL (N_*S_)    // 8128

// fused single-launch kernel
#define BM   16
#define GBLK (M_TOTAL/BM)  // 508 blocks
#define BK   64            // K-tile
#define NKT  (D_/BK)       // 8
#define ASTR 72            // A row stride (bf16): 144 B, 16B-aligned
#define HSTR 320           // epilogue h stride (floats)
#define LDS_A_BYTES (BM*ASTR*2)   // 2304
#define LDS_B_BYTES (OUTP*BK*2)   // 40960 (linear + XOR swizzle)
#define LDS_TOTAL   (LDS_A_BYTES + LDS_B_BYTES)   // 43264

typedef __attribute__((ext_vector_type(4))) float  float4v;
typedef __attribute__((ext_vector_type(8))) __bf16 bf16x8;
typedef __attribute__((ext_vector_type(4))) __bf16 bf16x4;

// ---------------------------------------------------------------------------
// enc_v9: SINGLE LAUNCH. r5's exact pacing structure (best measured), with
// prep_small absorbed:
//  - B is staged per tile straight from w_lin (f32, L2-resident) with inline
//    f32->bf16 conversion at commit; rows >=300 stored as zeros. Same
//    rounding as the old prep conversion -> bit-identical output.
//  - use = t1[:,0,:] copy folded into the epilogue (17 groups/block).
// Everything else (A pacing, swizzled B-LDS, 2 barriers/tile, LN) is r5.
// ---------------------------------------------------------------------------
__global__ __launch_bounds__(256, 2) void enc_v9(
    const float* __restrict__ t1, const int* __restrict__ wseq,
    const float* __restrict__ w_lin, const float* __restrict__ b_lin,
    const float* __restrict__ gamma, const float* __restrict__ beta,
    float* __restrict__ out)
{
    __shared__ __align__(16) char smem[LDS_TOTAL];
    __bf16* Alds  = (__bf16*)smem;              // [16][72]
    char*   Bbase = smem + LDS_A_BYTES;         // [320][128B] swizzled
    float*  hlds  = (float*)Bbase;              // [16][320] aliases B after k-loop

    const int tid  = threadIdx.x;
    const int blk  = blockIdx.x;
    const int m0   = blk * BM;
    const int lane = tid & 63;
    const int wave = tid >> 6;         // 0..3 -> col tiles [wave*5, wave*5+5)
    const int quad = lane >> 4;
    const int ln16 = lane & 15;

    // ---- A staging role: one (row, 16B k-group) per thread
    const int ar  = tid >> 4;          // 0..15
    const int akg = tid & 15;          // 0..15 -> covers 64 floats = BK
    const int sp  = m0 + ar;
    const int nn  = sp / S_;
    const int2 wv = *(const int2*)(wseq + sp * 2);
    const int st  = min(wv.x, L_ - 3);
    const int en  = min(wv.y, L_ - 2);
    const int cnt = en - st;
    const float inv = 1.0f / (float)cnt;
    const float* abase = t1 + ((size_t)nn * L_ + 1 + st) * D_ + akg * 4;

    // ---- B staging role: 20 chunks of 4 f32; chunk it -> (row o, 8B col kq)
    // o = (tid+it*256)>>4 in 0..319, kq = (tid+it*256)&15
    // swizzled LDS byte: (o*128 + kq*8) ^ ((o&7)<<4)  [XOR hits bits 4-6 only]

    // ---- prologue: prefetch tile 0 (A from t1, B from w_lin f32)
    float4v aload[8];
    #pragma unroll
    for (int j = 0; j < 8; ++j) {
        int jj = (j < cnt) ? j : (cnt - 1);        // clamp keeps addr in-bounds
        aload[j] = *(const float4v*)(abase + jj * D_);
    }
    float4v bloadF[20];
    #pragma unroll
    for (int it = 0; it < 20; ++it) {
        int idx = tid + it * 256;
        int o = idx >> 4, kq = idx & 15;
        if (o < OUT_)
            bloadF[it] = *(const float4v*)(w_lin + (size_t)o * D_ + kq * 4);
        else
            bloadF[it] = float4v{0.f, 0.f, 0.f, 0.f};
    }

    float4v acc[5];
    #pragma unroll
    for (int i = 0; i < 5; ++i) acc[i] = float4v{0.f, 0.f, 0.f, 0.f};

    #pragma unroll
    for (int kt = 0; kt < NKT; ++kt) {
        // ---- commit tile kt: A mean -> LDS, B cvt f32->bf16 -> swizzled LDS
        float4v s4 = {0.f, 0.f, 0.f, 0.f};
        #pragma unroll
        for (int j = 0; j < 8; ++j)
            if (j < cnt) s4 += aload[j];
        s4 *= inv;
        bf16x4 a4;
        a4[0] = (__bf16)s4[0]; a4[1] = (__bf16)s4[1];
        a4[2] = (__bf16)s4[2]; a4[3] = (__bf16)s4[3];
        *(bf16x4*)(Alds + ar * ASTR + akg * 4) = a4;

        #pragma unroll
        for (int it = 0; it < 20; ++it) {
            int idx = tid + it * 256;
            int o = idx >> 4, kq = idx & 15;
            bf16x4 b4;
            b4[0] = (__bf16)bloadF[it][0]; b4[1] = (__bf16)bloadF[it][1];
            b4[2] = (__bf16)bloadF[it][2]; b4[3] = (__bf16)bloadF[it][3];
            int off = (o * 128 + kq * 8) ^ ((o & 7) << 4);   // XOR swizzle
            *(bf16x4*)(Bbase + off) = b4;
        }
        __syncthreads();   // barrier #1 — tile kt visible

        // ---- prefetch tile kt+1 (regs survive barriers): B then A
        if (kt < NKT - 1) {
            const float* wsrc = w_lin + (kt + 1) * BK;
            #pragma unroll
            for (int it = 0; it < 20; ++it) {
                int idx = tid + it * 256;
                int o = idx >> 4, kq = idx & 15;
                if (o < OUT_)
                    bloadF[it] = *(const float4v*)(wsrc + (size_t)o * D_ + kq * 4);
            }
            #pragma unroll
            for (int j = 0; j < 8; ++j) {
                int jj = (j < cnt) ? j : (cnt - 1);
                aload[j] = *(const float4v*)(abase + (kt + 1) * BK + jj * D_);
            }
        }

        // ---- MFMA tile kt: 2 k-steps x 5 col-tiles (r5-identical)
        #pragma unroll
        for (int ks = 0; ks < 2; ++ks) {
            bf16x8 af = *(const bf16x8*)(Alds + ln16 * ASTR + ks * 32 + quad * 8);
            #pragma unroll
            for (int i = 0; i < 5; ++i) {
                const int orow = (wave * 5 + i) * 16 + ln16;
                const int slot = ((ks * 4 + quad) ^ (orow & 7)) << 4;
                bf16x8 bfr = *(const bf16x8*)(Bbase + orow * 128 + slot);
                acc[i] = __builtin_amdgcn_mfma_f32_16x16x32_bf16(af, bfr, acc[i], 0, 0, 0);
            }
        }
        __syncthreads();   // barrier #2 — reads done before next tile overwrite
    }

    // ---- epilogue: h = acc + bias (C layout: row = quad*4+reg, col = ln16)
    #pragma unroll
    for (int i = 0; i < 5; ++i) {
        const int col = (wave * 5 + i) * 16 + ln16;
        const float bl = (col < OUT_) ? b_lin[col] : 0.0f;
        #pragma unroll
        for (int r = 0; r < 4; ++r)
            hlds[(quad * 4 + r) * HSTR + col] = acc[i][r] + bl;
    }
    __syncthreads();

    // ---- LayerNorm over 300 cols; 16 threads/row, shfl-reduce in 16-lane groups
    const int r  = tid >> 4;           // 0..15
    const int c0 = tid & 15;
    float sum = 0.f, sq = 0.f;
    #pragma unroll
    for (int i = 0; i < 19; ++i) {
        int c = c0 + 16 * i;
        if (c < OUT_) { float v = hlds[r * HSTR + c]; sum += v; sq += v * v; }
    }
    #pragma unroll
    for (int off = 8; off > 0; off >>= 1) {
        sum += __shfl_xor(sum, off);
        sq  += __shfl_xor(sq,  off);
    }
    const float mu  = sum * (1.0f / OUT_);
    const float var = sq * (1.0f / OUT_) - mu * mu;
    const float rs  = rsqrtf(var + EPS_);
    float* orow = out + (size_t)(m0 + r) * OUT_;
    #pragma unroll
    for (int i = 0; i < 19; ++i) {
        int c = c0 + 16 * i;
        if (c < OUT_) {
            float v = hlds[r * HSTR + c];
            orow[c] = (v - mu) * rs * gamma[c] + beta[c];
        }
    }

    // ---- folded use-copy: use = t1[:,0,:] (8192 float4 groups over 508 blocks)
    float* use_out = out + (size_t)M_TOTAL * OUT_;
    if (tid < 17) {
        int g = blk + tid * GBLK;               // stride-508 coverage, 17 slots
        if (g < N_ * (D_ / 4)) {
            int n = g >> 7, dg = g & 127;
            float4v v = *(const float4v*)(t1 + (size_t)n * L_ * D_ + dg * 4);
            *(float4v*)(use_out + n * D_ + dg * 4) = v;
        }
    }
}

extern "C" void kernel_launch(void* const* d_in, const int* in_sizes, int n_in,
                              void* d_out, int out_size, void* d_ws, size_t ws_size,
                              hipStream_t stream) {
    const float* t1    = (const float*)d_in[0];
    const int*   wseq  = (const int*)d_in[1];   // word_seq (int32); d_in[2] mask unused
    const float* w_lin = (const float*)d_in[3];
    const float* b_lin = (const float*)d_in[4];
    const float* gamma = (const float*)d_in[5];
    const float* beta  = (const float*)d_in[6];
    float* out  = (float*)d_out;

    enc_v9<<<GBLK, 256, 0, stream>>>(t1, wseq, w_lin, b_lin, gamma, beta, out);
}